// Round 4
// baseline (3669.329 us; speedup 1.0000x reference)
//
#include <hip/hip_runtime.h>
#include <cmath>

#define BROWS 16384
#define CDIM  1024
#define NIT   16

typedef __attribute__((ext_vector_type(8))) short short8;
typedef __attribute__((ext_vector_type(4))) short short4v;
typedef __attribute__((ext_vector_type(4))) float floatx4;

__device__ __forceinline__ unsigned short f2bf(float f) {
  union { float f; unsigned u; } x; x.f = f;
  unsigned r = x.u + 0x7fffu + ((x.u >> 16) & 1u);  // RNE
  return (unsigned short)(r >> 16);
}
__device__ __forceinline__ float bf2f(unsigned short h) {
  union { float f; unsigned u; } x; x.u = ((unsigned)h) << 16;
  return x.f;
}

// ---- weights fp32 -> bf16, straight + transposed, LDS-tiled (coalesced) ----
__global__ void prep_weights(const float* __restrict__ W1, const float* __restrict__ W2,
                             const float* __restrict__ W3,
                             unsigned short* __restrict__ Wb, unsigned short* __restrict__ Wt) {
  __shared__ unsigned short tile[64 * 65];
  const int bid = blockIdx.x;                 // 3 * 16 * 16
  const int m = bid >> 8, rem = bid & 255;
  const int r0 = (rem >> 4) * 64, c0 = (rem & 15) * 64;
  const float* W = (m == 0) ? W1 : ((m == 1) ? W2 : W3);
  const int t = threadIdx.x;
#pragma unroll
  for (int i = 0; i < 16; i++) {
    int idx = i * 256 + t;                    // 0..4095
    int r = idx >> 6, c = idx & 63;
    unsigned short b = f2bf(W[(size_t)(r0 + r) * CDIM + c0 + c]);
    Wb[(m << 20) + (size_t)(r0 + r) * CDIM + c0 + c] = b;
    tile[c * 65 + r] = b;
  }
  __syncthreads();
#pragma unroll
  for (int i = 0; i < 16; i++) {
    int idx = i * 256 + t;
    int cr = idx >> 6, cc = idx & 63;
    Wt[(m << 20) + (size_t)(c0 + cr) * CDIM + r0 + cc] = tile[cr * 65 + cc];
  }
}

__global__ void conv_inputs(const float* __restrict__ y, const float* __restrict__ v,
                            unsigned short* __restrict__ ybf, unsigned short* __restrict__ wbf,
                            float* __restrict__ inner) {
  int i = (blockIdx.x * 256 + threadIdx.x) * 4;   // vectorized x4
  floatx4 yv = *(const floatx4*)(y + i);
  floatx4 vv = *(const floatx4*)(v + i);
  short4v a, b;
#pragma unroll
  for (int r = 0; r < 4; r++) { a[r] = (short)f2bf(yv[r]); b[r] = (short)f2bf(vv[r]); }
  *(short4v*)(ybf + i) = a;
  *(short4v*)(wbf + i) = b;
  if (i < NIT * BROWS) *(floatx4*)(inner + i) = floatx4{0.f, 0.f, 0.f, 0.f};
}

// v fp32 -> bf16 into the (free after GEMM1) ybf buffer
__global__ void conv_v(const float* __restrict__ v, unsigned short* __restrict__ vb) {
  int i = (blockIdx.x * 256 + threadIdx.x) * 8;
  floatx4 a = *(const floatx4*)(v + i);
  floatx4 b = *(const floatx4*)(v + i + 4);
  short8 o;
#pragma unroll
  for (int r = 0; r < 4; r++) { o[r] = (short)f2bf(a[r]); o[r + 4] = (short)f2bf(b[r]); }
  *(short8*)(vb + i) = o;
}

// ---- Zero-barrier single-wave GEMM: C[m,n] = sum_k A[m,k]*B[n,k] ----
// One wave (64 thr) per block computes a 128m x 64n tile. The wave stages its
// own A/B tiles via global_load_lds and tracks arrival with ITS OWN vmcnt
// (s_waitcnt vmcnt(12) -- never 0, never a barrier). Prefetch distance = 2
// K-tiles (~2 compute phases) covers L2/LLC latency.
// MODE 0: FWD   outB=bf16(elu(acc+bias)), outD=bf16(elu')
// MODE 1: FWD3  outZ = acc + bias + yin (fp32)
// MODE 2: BWD   outB = bf16(acc * Dm)
// MODE 3: BWD3  outB = bf16(acc); inner[row] += sum_n acc*vin
template <int MODE>
__global__ __launch_bounds__(64, 2)
void gemm_w(const unsigned short* __restrict__ A,
            const unsigned short* __restrict__ Bm,
            const float* __restrict__ bias,
            const float* __restrict__ yin,
            const unsigned short* __restrict__ Dm,
            const unsigned short* __restrict__ vin,
            unsigned short* __restrict__ outB,
            unsigned short* __restrict__ outD,
            float* __restrict__ outZ,
            float* __restrict__ inner) {
  constexpr int K = CDIM, N = CDIM;
  // Two stages x (A 128x32 + B 64x32) = 12288 elems = 24 KB. Epilogue reuses
  // it as a 128x68 bf16 transpose tile (8704 elems).
  __shared__ unsigned short smem[12288];

  const int t = threadIdx.x;                   // 0..63 (one wave)
  const int lb = blockIdx.x;                   // 0..2047
  // XCD swizzle: xcd = lb&7 owns a contiguous 16-m-tile slab; n cycles fastest.
  const int idx = lb >> 3;                     // 0..255
  const int m0 = ((lb & 7) * 16 + (idx >> 4)) * 128;
  const int n0 = (idx & 15) * 64;

  const int quad = t >> 4, ln = t & 15;
  const int srow = t >> 2;                     // 0..15 (row within 16-row group)
  const int sk = ((t & 3) * 8) ^ (((srow >> 1) & 3) * 8);  // bank-swizzled k

  const unsigned short* gA = A + (size_t)(m0 + srow) * K + sk;
  const unsigned short* gB = Bm + (size_t)(n0 + srow) * K + sk;

  // frag read offsets (swizzle folded in): A rows = mi*16+ln, B rows = ni*16+ln
  const int xorK = ((ln >> 1) & 3) * 8;
  const int raoff = ln * 32 + ((quad * 8) ^ xorK);         // + mi*512
  const int rboff = 4096 + ln * 32 + ((quad * 8) ^ xorK);  // + ni*512

  floatx4 acc[8][4];
#pragma unroll
  for (int i = 0; i < 8; i++)
#pragma unroll
    for (int j = 0; j < 4; j++) acc[i][j] = {0.f, 0.f, 0.f, 0.f};

  // stage tile k0 (elems) into buffer at LDS elem-offset bufb
#define STAGE(k0, bufb)                                                                          \
  do {                                                                                           \
    _Pragma("unroll")                                                                            \
    for (int i = 0; i < 8; i++)                                                                  \
      __builtin_amdgcn_global_load_lds(                                                          \
          (const __attribute__((address_space(1))) void*)(gA + (size_t)i * 16 * K + (k0)),       \
          (__attribute__((address_space(3))) void*)&smem[(bufb) + i * 512 + t * 8], 16, 0, 0);   \
    _Pragma("unroll")                                                                            \
    for (int j = 0; j < 4; j++)                                                                  \
      __builtin_amdgcn_global_load_lds(                                                          \
          (const __attribute__((address_space(1))) void*)(gB + (size_t)j * 16 * K + (k0)),       \
          (__attribute__((address_space(3))) void*)&smem[(bufb) + 4096 + j * 512 + t * 8], 16, 0, 0); \
  } while (0)

  // body of one K-step; WAIT = s_waitcnt imm (vmcnt such that tile kk has landed)
#define KSTEP(kk, WAIT, DO_STAGE)                                                                \
  do {                                                                                           \
    const int buf = ((kk) & 1) * 6144;                                                           \
    __builtin_amdgcn_s_waitcnt(WAIT);                                                            \
    short8 aF[8], bF[4];                                                                         \
    _Pragma("unroll")                                                                            \
    for (int mi = 0; mi < 8; mi++) aF[mi] = *(const short8*)&smem[buf + raoff + mi * 512];       \
    _Pragma("unroll")                                                                            \
    for (int ni = 0; ni < 4; ni++) bF[ni] = *(const short8*)&smem[buf + rboff + ni * 512];       \
    __builtin_amdgcn_s_waitcnt(0xC07F); /* lgkmcnt(0): frags in regs before overwrite */         \
    if (DO_STAGE) STAGE(((kk) + 2) * 32, buf);                                                   \
    _Pragma("unroll")                                                                            \
    for (int mi = 0; mi < 8; mi++)                                                               \
      _Pragma("unroll")                                                                          \
      for (int ni = 0; ni < 4; ni++)                                                             \
        acc[mi][ni] = __builtin_amdgcn_mfma_f32_16x16x32_bf16(aF[mi], bF[ni], acc[mi][ni], 0, 0, 0); \
  } while (0)

  STAGE(0, 0);
  STAGE(32, 6144);
  // 0xF7C: vmcnt(12) lgkmcnt(15) expcnt(7) -> wait until only newest 12 vmem
  // (tile kk+1's stage) outstanding => tile kk fully in LDS. Never vmcnt(0).
#pragma unroll 2
  for (int kk = 0; kk < 30; kk++) KSTEP(kk, 0xF7C, 1);
  KSTEP(30, 0xF7C, 0);
  KSTEP(31, 0xF70, 0);   // vmcnt(0) only for the final tile
#undef KSTEP
#undef STAGE

  // ---- epilogue (single wave -- no barrier needed): transpose via LDS, then
  // coalesced global I/O ----
  unsigned short* Ct = smem;                   // 128 x 68
  const int lrow = quad * 4;

  if (MODE == 0) {
    float bv[4];
#pragma unroll
    for (int ni = 0; ni < 4; ni++) bv[ni] = bias[n0 + ni * 16 + ln];
#pragma unroll
    for (int mi = 0; mi < 8; mi++)
#pragma unroll
      for (int ni = 0; ni < 4; ni++)
#pragma unroll
        for (int r = 0; r < 4; r++) {
          float p = acc[mi][ni][r] + bv[ni];
          float e = (p > 0.f) ? p : expm1f(p);
          Ct[(mi * 16 + lrow + r) * 68 + ni * 16 + ln] = f2bf(e);
        }
  } else {
#pragma unroll
    for (int mi = 0; mi < 8; mi++)
#pragma unroll
      for (int ni = 0; ni < 4; ni++)
#pragma unroll
        for (int r = 0; r < 4; r++)
          Ct[(mi * 16 + lrow + r) * 68 + ni * 16 + ln] = f2bf(acc[mi][ni][r]);
  }

  const int orow = t >> 3;                     // 0..7
  const int ocol = (t & 7) * 8;                // 0..56
#pragma unroll
  for (int it = 0; it < 16; it++) {
    const int lr = it * 8 + orow;
    short4v v0 = *(const short4v*)&Ct[lr * 68 + ocol];
    short4v v1 = *(const short4v*)&Ct[lr * 68 + ocol + 4];
    short8 val;
#pragma unroll
    for (int i = 0; i < 4; i++) { val[i] = v0[i]; val[i + 4] = v1[i]; }
    const size_t o = (size_t)(m0 + lr) * N + (n0 + ocol);
    if (MODE == 0) {
      *(short8*)&outB[o] = val;
      short8 dd;
#pragma unroll
      for (int i = 0; i < 8; i++) {
        float e = bf2f((unsigned short)val[i]);
        dd[i] = (short)f2bf(e > 0.f ? 1.f : e + 1.f);   // elu' from staged elu
      }
      *(short8*)&outD[o] = dd;
    } else if (MODE == 1) {
      const floatx4 y0 = *(const floatx4*)&yin[o];
      const floatx4 y1 = *(const floatx4*)&yin[o + 4];
      const floatx4 b0 = *(const floatx4*)&bias[n0 + ocol];
      const floatx4 b1 = *(const floatx4*)&bias[n0 + ocol + 4];
      floatx4 z0, z1;
#pragma unroll
      for (int i = 0; i < 4; i++) {
        z0[i] = bf2f((unsigned short)val[i]) + b0[i] + y0[i];
        z1[i] = bf2f((unsigned short)val[i + 4]) + b1[i] + y1[i];
      }
      *(floatx4*)&outZ[o] = z0;
      *(floatx4*)&outZ[o + 4] = z1;
    } else if (MODE == 2) {
      short8 d = *(const short8*)&Dm[o];
      short8 ov;
#pragma unroll
      for (int i = 0; i < 8; i++)
        ov[i] = (short)f2bf(bf2f((unsigned short)val[i]) * bf2f((unsigned short)d[i]));
      *(short8*)&outB[o] = ov;
    } else {  // MODE 3
      *(short8*)&outB[o] = val;
      short8 vv = *(const short8*)&vin[o];
      float ps = 0.f;
#pragma unroll
      for (int i = 0; i < 8; i++)
        ps += bf2f((unsigned short)val[i]) * bf2f((unsigned short)vv[i]);
      ps += __shfl_xor(ps, 1);
      ps += __shfl_xor(ps, 2);
      ps += __shfl_xor(ps, 4);
      if ((t & 7) == 0) atomicAdd(&inner[m0 + lr], ps);
    }
  }
}

__global__ void combine_ldj(const float* __restrict__ ldj_in, const float* __restrict__ inner,
                            float* __restrict__ out) {
  int b = blockIdx.x * 256 + threadIdx.x;
  if (b < BROWS) {
    float a = ldj_in[b];
#pragma unroll
    for (int k = 1; k <= NIT; k++) {
      float s = (k & 1) ? 1.f : -1.f;       // odd k: +, even k: -
      a += s * inner[(k - 1) * BROWS + b] / (float)k;
    }
    out[b] = a;
  }
}

extern "C" void kernel_launch(void* const* d_in, const int* in_sizes, int n_in,
                              void* d_out, int out_size, void* d_ws, size_t ws_size,
                              hipStream_t stream) {
  const float* y   = (const float*)d_in[0];
  const float* ldj = (const float*)d_in[1];
  const float* v   = (const float*)d_in[2];
  const float* W1  = (const float*)d_in[3];
  const float* b1  = (const float*)d_in[4];
  const float* W2  = (const float*)d_in[5];
  const float* b2  = (const float*)d_in[6];
  const float* W3  = (const float*)d_in[7];
  const float* b3  = (const float*)d_in[8];

  float* z_out   = (float*)d_out;                         // B*C fp32
  float* ldj_out = z_out + (size_t)BROWS * CDIM;          // B fp32

  const size_t MC = (size_t)BROWS * CDIM;                 // 16M elems
  const size_t WW = (size_t)3 * CDIM * CDIM;              // 3M elems
  unsigned short* Wb    = (unsigned short*)d_ws;          // 6 MB
  unsigned short* Wt    = Wb + WW;                        // 6 MB
  float*          inner = (float*)(Wt + WW);              // 1 MB
  unsigned short* ybf   = (unsigned short*)(inner + NIT * BROWS);
  unsigned short* ua    = ybf + MC;                       // 32 MB each
  unsigned short* ub    = ua + MC;
  unsigned short* wv    = ub + MC;
  unsigned short* d1    = wv + MC;
  unsigned short* d2    = d1 + MC;

  prep_weights<<<768, 256, 0, stream>>>(W1, W2, W3, Wb, Wt);
  conv_inputs<<<(BROWS * CDIM) / (256 * 4), 256, 0, stream>>>(y, v, ybf, wv, inner);

  dim3 grid(2048);  // (16384/128) m-tiles x (1024/64) n-tiles, XCD-swizzled

  // forward: h1=elu(y@W1^T+b1), h2=elu(h1@W2^T+b2), z=y+h2@W3^T+b3
  gemm_w<0><<<grid, 64, 0, stream>>>(ybf, Wb,             b1, nullptr, nullptr, nullptr, ua, d1, nullptr, nullptr);
  // ybf free after GEMM1 -> bf16(v)
  conv_v<<<(BROWS * CDIM) / (256 * 8), 256, 0, stream>>>(v, ybf);
  gemm_w<0><<<grid, 64, 0, stream>>>(ua,  Wb + (1 << 20), b2, nullptr, nullptr, nullptr, ub, d2, nullptr, nullptr);
  gemm_w<1><<<grid, 64, 0, stream>>>(ub,  Wb + (2 << 20), b3, y,       nullptr, nullptr, nullptr, nullptr, z_out, nullptr);

  // power series: w <- ((w@W3)*d2 @ W2)*d1 @ W1 ; inner_k = <w, v>
  for (int k = 1; k <= NIT; k++) {
    gemm_w<2><<<grid, 64, 0, stream>>>(wv, Wt + (2 << 20), nullptr, nullptr, d2, nullptr, ua, nullptr, nullptr, nullptr);
    gemm_w<2><<<grid, 64, 0, stream>>>(ua, Wt + (1 << 20), nullptr, nullptr, d1, nullptr, ub, nullptr, nullptr, nullptr);
    gemm_w<3><<<grid, 64, 0, stream>>>(ub, Wt,             nullptr, nullptr, nullptr, ybf, wv, nullptr, nullptr, inner + (size_t)(k - 1) * BROWS);
  }

  combine_ldj<<<(BROWS + 255) / 256, 256, 0, stream>>>(ldj, inner, ldj_out);
}